// Round 8
// baseline (168.195 us; speedup 1.0000x reference)
//
#include <hip/hip_runtime.h>
#include <hip/hip_bf16.h>

#define B_N 16384
#define TAU 0.25f
#define GS 68     // G leading dim (floats); 16B-aligned rows
#define YS 133    // Y leading dim (floats); ODD -> scalar access conflict-free

typedef float f32x4 __attribute__((ext_vector_type(4)));
typedef short s16x8 __attribute__((ext_vector_type(8)));

__device__ __forceinline__ void gl_lds16(const void* g, void* l) {
    __builtin_amdgcn_global_load_lds(
        (const __attribute__((address_space(1))) void*)g,
        (__attribute__((address_space(3))) void*)l, 16, 0, 0);
}

__device__ __forceinline__ unsigned short bf16_bits(float v) {
    __hip_bfloat16 h = __float2bfloat16(v);
    return *reinterpret_cast<unsigned short*>(&h);
}

// ---------------------------------------------------------------------------
// Kernel 1: convert. x -> xh bf16 + row norms; zero loss accumulator.
// 256 blocks x 256 threads, 32 floats/thread (latency spread over all CUs).
// ---------------------------------------------------------------------------
__global__ __launch_bounds__(256) void convert_kernel(const float* __restrict__ x,
                                                      unsigned short* __restrict__ xh,
                                                      float* __restrict__ nrm,
                                                      float* __restrict__ out) {
    const int gid = blockIdx.x * 256 + threadIdx.x;   // 0..65535 quarter-rows
    if (gid == 0) out[0] = 0.0f;
    const size_t base = (size_t)gid * 32;
    float s = 0.0f;
    #pragma unroll
    for (int c = 0; c < 8; ++c) {
        const f32x4 v = ((const f32x4*)(x + base))[c];
        s += v.x * v.x + v.y * v.y + v.z * v.z + v.w * v.w;
        ushort4 h;
        h.x = bf16_bits(v.x); h.y = bf16_bits(v.y);
        h.z = bf16_bits(v.z); h.w = bf16_bits(v.w);
        ((ushort4*)(xh + base))[c] = h;
    }
    s += __shfl_xor(s, 1, 64);
    s += __shfl_xor(s, 2, 64);
    if ((gid & 3) == 0) nrm[gid >> 2] = s;
}

// ---------------------------------------------------------------------------
// Kernel 2: per-cluster prep (64 blocks). Q_n^T = L_n^{-1} D_n^T.
//   A: stage D^T into Y (YS=133: staging writes & all scalar reads <=2-way)
//   B: gram G = D^T D read directly from GLOBAL (Dn is 32 KB, L1-resident)
//   C: blocked Cholesky, register-resident 8x8 panels (wave 0) + rank-8 updates
//   D: invert 8x8 diag blocks (64 threads, registers)
//   E: block forward substitution, thread-per-column, same-thread chains only
//   F: emit Bht bf16 (B-operand layout) + Qg fp32 (rescore)
// ---------------------------------------------------------------------------
__global__ __launch_bounds__(256) void prep_kernel(const float* __restrict__ D,
                                                   float* __restrict__ Qg,
                                                   unsigned short* __restrict__ Bht) {
    __shared__ float Y[64 * YS];                      // D^T -> Q^T (in place)
    __shared__ __align__(16) float G[64 * GS + 64];   // gram -> L; tail = 1/L[i][i]
    __shared__ __align__(16) float Lti[8 * 8 * 8];    // 8x8 diag-block inverses
    const int t = threadIdx.x;
    const int n = blockIdx.x;
    const float* Dn = D + (size_t)n * 8192;

    // Phase A: Y[j][c] = Dn[c][j]  (coalesced f32x4 global reads; <=2-way LDS)
    for (int e4 = t; e4 < 2048; e4 += 256) {
        const int c = e4 >> 4, j4 = (e4 & 15) * 4;
        const f32x4 v = ((const f32x4*)Dn)[e4];
        Y[(j4 + 0) * YS + c] = v.x;
        Y[(j4 + 1) * YS + c] = v.y;
        Y[(j4 + 2) * YS + c] = v.z;
        Y[(j4 + 3) * YS + c] = v.w;
    }

    // Phase B: gram from global (L1-hot, no LDS bank traffic)
    {
        const int a0 = (t & 15) * 4, b0 = (t >> 4) * 4;
        float acc[4][4] = {};
        #pragma unroll 4
        for (int i = 0; i < 128; ++i) {
            const f32x4 av = *(const f32x4*)(Dn + i * 64 + a0);
            const f32x4 bv = *(const f32x4*)(Dn + i * 64 + b0);
            const float aa[4] = {av.x, av.y, av.z, av.w};
            const float bb[4] = {bv.x, bv.y, bv.z, bv.w};
            #pragma unroll
            for (int p = 0; p < 4; ++p)
                #pragma unroll
                for (int q = 0; q < 4; ++q) acc[p][q] = fmaf(aa[p], bb[q], acc[p][q]);
        }
        #pragma unroll
        for (int p = 0; p < 4; ++p)
            #pragma unroll
            for (int q = 0; q < 4; ++q) G[(a0 + p) * GS + b0 + q] = acc[p][q];
    }
    __syncthreads();

    // Phase C: blocked Cholesky, register-resident 8x8 panel factors
    for (int p8 = 0; p8 < 8; ++p8) {
        const int pb = p8 * 8;
        if (t < 64) {   // wave 0
            const int lane = t;
            const f32x4 v0 = *(const f32x4*)&G[lane * GS + pb];
            const f32x4 v1 = *(const f32x4*)&G[lane * GS + pb + 4];
            float g[8] = {v0.x, v0.y, v0.z, v0.w, v1.x, v1.y, v1.z, v1.w};
            #pragma unroll
            for (int kk = 0; kk < 8; ++kk) {
                const int k = pb + kk;
                const float dk = __shfl(g[kk], k, 64);
                const float rinv = 1.0f / sqrtf(dk);
                const float lik = g[kk] * rinv;
                g[kk] = lik;
                if (lane == 0) G[64 * GS + k] = rinv;
                #pragma unroll
                for (int jj = kk + 1; jj < 8; ++jj) {
                    const float ljk = __shfl(lik, pb + jj, 64);
                    g[jj] -= lik * ljk;
                }
            }
            *(f32x4*)&G[lane * GS + pb]     = (f32x4){g[0], g[1], g[2], g[3]};
            *(f32x4*)&G[lane * GS + pb + 4] = (f32x4){g[4], g[5], g[6], g[7]};
        }
        __syncthreads();
        const int base = pb + 8;
        if (base < 64) {   // rank-8 trailing update, all 256 threads
            for (int i = base + (t >> 5); i < 64; i += 8) {
                const f32x4 Li0 = *(const f32x4*)&G[i * GS + pb];
                const f32x4 Li1 = *(const f32x4*)&G[i * GS + pb + 4];
                for (int j = base + (t & 31); j < 64; j += 32) {
                    const f32x4 Lj0 = *(const f32x4*)&G[j * GS + pb];
                    const f32x4 Lj1 = *(const f32x4*)&G[j * GS + pb + 4];
                    float s = G[i * GS + j];
                    s -= Li0.x * Lj0.x + Li0.y * Lj0.y + Li0.z * Lj0.z + Li0.w * Lj0.w;
                    s -= Li1.x * Lj1.x + Li1.y * Lj1.y + Li1.z * Lj1.z + Li1.w * Lj1.w;
                    G[i * GS + j] = s;
                }
            }
        }
        __syncthreads();
    }

    // Phase D: invert 8x8 diagonal blocks independently. t<64: block bi, col c.
    if (t < 64) {
        const int bi = t >> 3, c = t & 7;
        const int base = bi * 8;
        float m[8];
        #pragma unroll
        for (int r = 0; r < 8; ++r) {
            float s = (r == c) ? 1.0f : 0.0f;
            #pragma unroll
            for (int k = 0; k < r; ++k)
                s -= G[(base + r) * GS + base + k] * m[k];
            m[r] = s * G[64 * GS + base + r];
        }
        #pragma unroll
        for (int r = 0; r < 8; ++r) Lti[(base + r) * 8 + c] = m[r];
    }
    __syncthreads();

    // Phase E: Q^T = L^{-1} D^T, block forward substitution; thread = column c.
    if (t < 128) {
        const int c = t;
        for (int i = 0; i < 8; ++i) {
            float Tv[8];
            #pragma unroll
            for (int r = 0; r < 8; ++r) Tv[r] = Y[(i * 8 + r) * YS + c];
            for (int k = 0; k < i; ++k) {
                #pragma unroll
                for (int kk = 0; kk < 8; ++kk) {
                    const float z = Y[(k * 8 + kk) * YS + c];
                    #pragma unroll
                    for (int r = 0; r < 8; ++r)
                        Tv[r] -= G[(i * 8 + r) * GS + k * 8 + kk] * z;
                }
            }
            #pragma unroll
            for (int r = 0; r < 8; ++r) {
                float z = 0.0f;
                #pragma unroll
                for (int rp = 0; rp <= r; ++rp)
                    z += Lti[(i * 8 + r) * 8 + rp] * Tv[rp];
                Y[(i * 8 + r) * YS + c] = z;
            }
        }
    }
    __syncthreads();

    // Phase F: outputs. Y[j][i] = Q^T.
    for (int e = t; e < 8192; e += 256) {
        const int j = e >> 7, i = e & 127;
        Bht[((size_t)n * 64 + j) * 128 + i] = bf16_bits(Y[j * YS + i]);
    }
    for (int e = t; e < 8192; e += 256) {
        const int i = e >> 6, j = e & 63;
        Qg[(size_t)n * 8192 + e] = Y[j * YS + i];
    }
}

// ---------------------------------------------------------------------------
// Kernel 3: MFMA scores, A-register-resident; per-mt epilogue interleaved so
// the VALU squared-sum reduction co-issues with the next mt's MFMAs.
// ---------------------------------------------------------------------------
__global__ __launch_bounds__(256) void gemm_scores(const unsigned short* __restrict__ xh,
                                                   const unsigned short* __restrict__ Bht,
                                                   float* __restrict__ S) {
    __shared__ unsigned short ldsA[128 * 128];   // 32 KB
    __shared__ unsigned short ldsB[128 * 128];   // 32 KB
    const int t = threadIdx.x, w = t >> 6, lane = t & 63;
    const int m0 = blockIdx.x * 128;
    const int nsplit = blockIdx.y;               // 16 clusters per split
    const int wm = w & 1, wn = w >> 1;

    // ---- stage A (once) and B tile 0 ----
    {
        const int rl = lane >> 4;                 // row within 4-row group
        const int p  = lane & 15;                 // physical colblock
        #pragma unroll
        for (int q = 0; q < 8; ++q) {
            const int row = w * 32 + q * 4 + rl;
            const int c = p ^ (row & 15);         // source colblock
            gl_lds16(xh + (size_t)(m0 + row) * 128 + c * 8,
                     &ldsA[(w * 32 + q * 4) * 128]);
            gl_lds16(Bht + (size_t)(nsplit * 1024 + row) * 128 + c * 8,
                     &ldsB[(w * 32 + q * 4) * 128]);
        }
    }
    __syncthreads();

    // ---- load all A-fragments into registers (64 VGPRs), resident ----
    s16x8 af[4][4];   // [mt][ks]
    #pragma unroll
    for (int mt = 0; mt < 4; ++mt) {
        const int r = wm * 64 + mt * 16 + (lane & 15);
        #pragma unroll
        for (int ks = 0; ks < 4; ++ks) {
            const int p = (ks * 4 + (lane >> 4)) ^ (lane & 15);
            af[mt][ks] = *(const s16x8*)&ldsA[r * 128 + p * 8];
        }
    }

    #pragma unroll 1
    for (int it = 0; it < 8; ++it) {
        // ---- read this tile's B-fragments ----
        s16x8 bf[4][4];   // [nt][ks]
        #pragma unroll
        for (int nt = 0; nt < 4; ++nt) {
            const int r = wn * 64 + nt * 16 + (lane & 15);
            #pragma unroll
            for (int ks = 0; ks < 4; ++ks) {
                const int p = (ks * 4 + (lane >> 4)) ^ (lane & 15);
                bf[nt][ks] = *(const s16x8*)&ldsB[r * 128 + p * 8];
            }
        }
        __syncthreads();   // all waves done reading ldsB (and ldsA on it=0)

        // ---- kick DMA for next B tile (overlaps the MFMAs below) ----
        if (it < 7) {
            const int rl = lane >> 4, p = lane & 15;
            #pragma unroll
            for (int q = 0; q < 8; ++q) {
                const int row = w * 32 + q * 4 + rl;
                const int c = p ^ (row & 15);
                gl_lds16(Bht + (size_t)(nsplit * 1024 + (it + 1) * 128 + row) * 128 + c * 8,
                         &ldsB[(w * 32 + q * 4) * 128]);
            }
        }

        // ---- MFMAs + interleaved per-mt epilogue ----
        const int nc = nsplit * 16 + it * 2 + wn;
        #pragma unroll
        for (int mt = 0; mt < 4; ++mt) {
            f32x4 acc[4];
            #pragma unroll
            for (int nt = 0; nt < 4; ++nt) acc[nt] = (f32x4){0.f, 0.f, 0.f, 0.f};
            #pragma unroll
            for (int ks = 0; ks < 4; ++ks)
                #pragma unroll
                for (int nt = 0; nt < 4; ++nt)
                    acc[nt] = __builtin_amdgcn_mfma_f32_16x16x32_bf16(
                        af[mt][ks], bf[nt][ks], acc[nt], 0, 0, 0);
            // epilogue for this mt (VALU; overlaps next mt's MFMA pipe)
            #pragma unroll
            for (int rg = 0; rg < 4; ++rg) {
                float p = 0.0f;
                #pragma unroll
                for (int nt = 0; nt < 4; ++nt) {
                    const float v = acc[nt][rg];
                    p += v * v;
                }
                p += __shfl_xor(p, 1, 64);
                p += __shfl_xor(p, 2, 64);
                p += __shfl_xor(p, 4, 64);
                p += __shfl_xor(p, 8, 64);
                if ((lane & 15) == 0) {
                    const int m = wm * 64 + mt * 16 + (lane >> 4) * 4 + rg;
                    S[(size_t)nc * B_N + m0 + m] = p;
                }
            }
        }
        __syncthreads();   // drains this wave's DMA -> ldsB holds tile it+1
    }
}

// ---------------------------------------------------------------------------
// Kernel 4: argmax + loss + exact rescore, LDS-transposed S tile.
// (byte-identical to R6/R7 — known-good)
// ---------------------------------------------------------------------------
__global__ __launch_bounds__(256) void argmax_rescore(const float* __restrict__ Sa,
                                                      const float* __restrict__ nrm,
                                                      const float* __restrict__ x,
                                                      const float* __restrict__ Qg,
                                                      float* __restrict__ out) {
    __shared__ float tile[64 * 65];   // [sample][n], 16640 B
    __shared__ int sflags[64];
    __shared__ int scnt;
    __shared__ float ssum;
    __shared__ float scorr[4];
    const int t = threadIdx.x, w = t >> 6, lane = t & 63;
    const int b0 = blockIdx.x * 64;
    if (t == 0) scnt = 0;

    // coalesced load + transpose: Sa[n][b0 + c] -> tile[c][n]
    for (int idx = t; idx < 1024; idx += 256) {
        const int n = idx >> 4, c4 = idx & 15;
        const f32x4 v = *(const f32x4*)&Sa[(size_t)n * B_N + b0 + c4 * 4];
        tile[(c4 * 4 + 0) * 65 + n] = v.x;
        tile[(c4 * 4 + 1) * 65 + n] = v.y;
        tile[(c4 * 4 + 2) * 65 + n] = v.z;
        tile[(c4 * 4 + 3) * 65 + n] = v.w;
    }
    __syncthreads();

    // per-thread argmax (wave 0), flag near-ties, wave-reduced loss
    if (t < 64) {
        float v1 = -1e30f, v2 = -1e30f;
        int n1 = 0;
        for (int n = 0; n < 64; ++n) {
            const float v = tile[t * 65 + n];
            if (v > v1) { v2 = v1; v1 = v; n1 = n; }
            else v2 = fmaxf(v2, v);
        }
        out[1 + b0 + t] = (float)n1;
        if (v1 - v2 < TAU) { const int i = atomicAdd(&scnt, 1); sflags[i] = t; }
        float err = nrm[b0 + t] - v1;
        for (int off = 32; off; off >>= 1) err += __shfl_xor(err, off, 64);
        if (t == 0) ssum = err;
    }
    if (lane == 0) scorr[w] = 0.0f;
    __syncthreads();

    // cooperative exact rescore of flagged samples (S column from LDS)
    const int nf = scnt;
    float corr = 0.0f;
    for (int f = w; f < nf; f += 4) {
        const int s = sflags[f];
        const int b2 = b0 + s;
        const float v = tile[s * 65 + lane];
        float vm = v;
        for (int off = 32; off; off >>= 1) vm = fmaxf(vm, __shfl_xor(vm, off, 64));
        unsigned long long mask = __ballot((vm - v) < TAU);
        float best = -1e30f;
        int bn = 0;
        while (mask) {
            const int nn = (int)__builtin_ctzll(mask);
            mask &= mask - 1;
            const float* Qn = Qg + (size_t)nn * 8192;
            const float* xb = x + (size_t)b2 * 128;
            float dot = 0.0f;
            #pragma unroll 8
            for (int i = 0; i < 128; ++i)
                dot = fmaf(Qn[i * 64 + lane], xb[i], dot);
            float sv = dot * dot;
            for (int off = 32; off; off >>= 1) sv += __shfl_xor(sv, off, 64);
            if (sv > best) { best = sv; bn = nn; }
        }
        if (lane == 0) {
            out[1 + b2] = (float)bn;
            corr += vm - best;   // replace approx top score with exact best
        }
    }
    if (lane == 0 && corr != 0.0f) scorr[w] += corr;
    __syncthreads();
    if (t == 0)
        atomicAdd(out, ssum + scorr[0] + scorr[1] + scorr[2] + scorr[3]);
}

// ---------------------------------------------------------------------------
extern "C" void kernel_launch(void* const* d_in, const int* in_sizes, int n_in,
                              void* d_out, int out_size, void* d_ws, size_t ws_size,
                              hipStream_t stream) {
    const float* x = (const float*)d_in[0];   // [16384, 128]
    const float* D = (const float*)d_in[1];   // [64, 128, 64]
    float* out = (float*)d_out;               // [1 + 16384]

    char* ws = (char*)d_ws;
    unsigned short* xh  = (unsigned short*)(ws);                 // 4 MB
    unsigned short* Bht = (unsigned short*)(ws + (4u << 20));    // 1 MB
    float* Qg           = (float*)(ws + (5u << 20));             // 2 MB
    float* Sa           = (float*)(ws + (7u << 20));             // 4 MB
    float* nrm          = (float*)(ws + (11u << 20));            // 64 KB

    convert_kernel<<<256, 256, 0, stream>>>(x, xh, nrm, out);
    prep_kernel<<<64, 256, 0, stream>>>(D, Qg, Bht);
    gemm_scores<<<dim3(128, 4), 256, 0, stream>>>(xh, Bht, Sa);
    argmax_rescore<<<256, 256, 0, stream>>>(Sa, nrm, x, Qg, out);
}

// Round 9
// 161.253 us; speedup vs baseline: 1.0431x; 1.0431x over previous
//
#include <hip/hip_runtime.h>
#include <hip/hip_bf16.h>

#define B_N 16384
#define TAU 0.25f
#define GS 68     // G leading dim (floats); 16B-aligned rows
#define YS 133    // Y leading dim (floats); ODD -> scalar access conflict-free

typedef float f32x4 __attribute__((ext_vector_type(4)));
typedef short s16x8 __attribute__((ext_vector_type(8)));

__device__ __forceinline__ void gl_lds16(const void* g, void* l) {
    __builtin_amdgcn_global_load_lds(
        (const __attribute__((address_space(1))) void*)g,
        (__attribute__((address_space(3))) void*)l, 16, 0, 0);
}

__device__ __forceinline__ unsigned short bf16_bits(float v) {
    __hip_bfloat16 h = __float2bfloat16(v);
    return *reinterpret_cast<unsigned short*>(&h);
}

// ---------------------------------------------------------------------------
// Kernel 1 (merged): blocks 0..63 = per-cluster prep (R8 phases, unchanged);
// blocks 64..319 = convert (zero LDS -> co-resides with prep on the same CUs,
// so its ~8 us hides under prep's runtime).
// ---------------------------------------------------------------------------
__global__ __launch_bounds__(256) void prep_convert(const float* __restrict__ x,
                                                    const float* __restrict__ D,
                                                    unsigned short* __restrict__ xh,
                                                    float* __restrict__ nrm,
                                                    float* __restrict__ Qg,
                                                    unsigned short* __restrict__ Bht,
                                                    float* __restrict__ out) {
    const int t = threadIdx.x;

    if (blockIdx.x >= 64) {
        // ---------------- convert path ----------------
        const int gid = (blockIdx.x - 64) * 256 + t;   // 0..65535 quarter-rows
        if (gid == 0) out[0] = 0.0f;
        const size_t base = (size_t)gid * 32;
        float s = 0.0f;
        #pragma unroll
        for (int c = 0; c < 8; ++c) {
            const f32x4 v = ((const f32x4*)(x + base))[c];
            s += v.x * v.x + v.y * v.y + v.z * v.z + v.w * v.w;
            ushort4 h;
            h.x = bf16_bits(v.x); h.y = bf16_bits(v.y);
            h.z = bf16_bits(v.z); h.w = bf16_bits(v.w);
            ((ushort4*)(xh + base))[c] = h;
        }
        s += __shfl_xor(s, 1, 64);
        s += __shfl_xor(s, 2, 64);
        if ((gid & 3) == 0) nrm[gid >> 2] = s;
        return;
    }

    // ---------------- prep path ----------------
    __shared__ float Y[64 * YS];                      // D^T -> Q^T (in place)
    __shared__ __align__(16) float G[64 * GS + 64];   // gram -> L; tail = 1/L[i][i]
    __shared__ __align__(16) float Lti[8 * 8 * 8];    // 8x8 diag-block inverses
    const int n = blockIdx.x;
    const float* Dn = D + (size_t)n * 8192;

    // Phase A: Y[j][c] = Dn[c][j]  (coalesced f32x4 global reads; <=2-way LDS)
    for (int e4 = t; e4 < 2048; e4 += 256) {
        const int c = e4 >> 4, j4 = (e4 & 15) * 4;
        const f32x4 v = ((const f32x4*)Dn)[e4];
        Y[(j4 + 0) * YS + c] = v.x;
        Y[(j4 + 1) * YS + c] = v.y;
        Y[(j4 + 2) * YS + c] = v.z;
        Y[(j4 + 3) * YS + c] = v.w;
    }

    // Phase B: gram from global (L1-hot, no LDS bank traffic)
    {
        const int a0 = (t & 15) * 4, b0 = (t >> 4) * 4;
        float acc[4][4] = {};
        #pragma unroll 4
        for (int i = 0; i < 128; ++i) {
            const f32x4 av = *(const f32x4*)(Dn + i * 64 + a0);
            const f32x4 bv = *(const f32x4*)(Dn + i * 64 + b0);
            const float aa[4] = {av.x, av.y, av.z, av.w};
            const float bb[4] = {bv.x, bv.y, bv.z, bv.w};
            #pragma unroll
            for (int p = 0; p < 4; ++p)
                #pragma unroll
                for (int q = 0; q < 4; ++q) acc[p][q] = fmaf(aa[p], bb[q], acc[p][q]);
        }
        #pragma unroll
        for (int p = 0; p < 4; ++p)
            #pragma unroll
            for (int q = 0; q < 4; ++q) G[(a0 + p) * GS + b0 + q] = acc[p][q];
    }
    __syncthreads();

    // Phase C: blocked Cholesky, register-resident 8x8 panel factors
    for (int p8 = 0; p8 < 8; ++p8) {
        const int pb = p8 * 8;
        if (t < 64) {   // wave 0
            const int lane = t;
            const f32x4 v0 = *(const f32x4*)&G[lane * GS + pb];
            const f32x4 v1 = *(const f32x4*)&G[lane * GS + pb + 4];
            float g[8] = {v0.x, v0.y, v0.z, v0.w, v1.x, v1.y, v1.z, v1.w};
            #pragma unroll
            for (int kk = 0; kk < 8; ++kk) {
                const int k = pb + kk;
                const float dk = __shfl(g[kk], k, 64);
                const float rinv = 1.0f / sqrtf(dk);
                const float lik = g[kk] * rinv;
                g[kk] = lik;
                if (lane == 0) G[64 * GS + k] = rinv;
                #pragma unroll
                for (int jj = kk + 1; jj < 8; ++jj) {
                    const float ljk = __shfl(lik, pb + jj, 64);
                    g[jj] -= lik * ljk;
                }
            }
            *(f32x4*)&G[lane * GS + pb]     = (f32x4){g[0], g[1], g[2], g[3]};
            *(f32x4*)&G[lane * GS + pb + 4] = (f32x4){g[4], g[5], g[6], g[7]};
        }
        __syncthreads();
        const int base = pb + 8;
        if (base < 64) {   // rank-8 trailing update, all 256 threads
            for (int i = base + (t >> 5); i < 64; i += 8) {
                const f32x4 Li0 = *(const f32x4*)&G[i * GS + pb];
                const f32x4 Li1 = *(const f32x4*)&G[i * GS + pb + 4];
                for (int j = base + (t & 31); j < 64; j += 32) {
                    const f32x4 Lj0 = *(const f32x4*)&G[j * GS + pb];
                    const f32x4 Lj1 = *(const f32x4*)&G[j * GS + pb + 4];
                    float s = G[i * GS + j];
                    s -= Li0.x * Lj0.x + Li0.y * Lj0.y + Li0.z * Lj0.z + Li0.w * Lj0.w;
                    s -= Li1.x * Lj1.x + Li1.y * Lj1.y + Li1.z * Lj1.z + Li1.w * Lj1.w;
                    G[i * GS + j] = s;
                }
            }
        }
        __syncthreads();
    }

    // Phase D: invert 8x8 diagonal blocks independently. t<64: block bi, col c.
    if (t < 64) {
        const int bi = t >> 3, c = t & 7;
        const int base = bi * 8;
        float m[8];
        #pragma unroll
        for (int r = 0; r < 8; ++r) {
            float s = (r == c) ? 1.0f : 0.0f;
            #pragma unroll
            for (int k = 0; k < r; ++k)
                s -= G[(base + r) * GS + base + k] * m[k];
            m[r] = s * G[64 * GS + base + r];
        }
        #pragma unroll
        for (int r = 0; r < 8; ++r) Lti[(base + r) * 8 + c] = m[r];
    }
    __syncthreads();

    // Phase E: Q^T = L^{-1} D^T, block forward substitution; thread = column c.
    if (t < 128) {
        const int c = t;
        for (int i = 0; i < 8; ++i) {
            float Tv[8];
            #pragma unroll
            for (int r = 0; r < 8; ++r) Tv[r] = Y[(i * 8 + r) * YS + c];
            for (int k = 0; k < i; ++k) {
                #pragma unroll
                for (int kk = 0; kk < 8; ++kk) {
                    const float z = Y[(k * 8 + kk) * YS + c];
                    #pragma unroll
                    for (int r = 0; r < 8; ++r)
                        Tv[r] -= G[(i * 8 + r) * GS + k * 8 + kk] * z;
                }
            }
            #pragma unroll
            for (int r = 0; r < 8; ++r) {
                float z = 0.0f;
                #pragma unroll
                for (int rp = 0; rp <= r; ++rp)
                    z += Lti[(i * 8 + r) * 8 + rp] * Tv[rp];
                Y[(i * 8 + r) * YS + c] = z;
            }
        }
    }
    __syncthreads();

    // Phase F: outputs. Y[j][i] = Q^T.
    for (int e = t; e < 8192; e += 256) {
        const int j = e >> 7, i = e & 127;
        Bht[((size_t)n * 64 + j) * 128 + i] = bf16_bits(Y[j * YS + i]);
    }
    for (int e = t; e < 8192; e += 256) {
        const int i = e >> 6, j = e & 63;
        Qg[(size_t)n * 8192 + e] = Y[j * YS + i];
    }
}

// ---------------------------------------------------------------------------
// Kernel 2: MFMA scores, A-register-resident; per-mt epilogue interleaved.
// (byte-identical to R8)
// ---------------------------------------------------------------------------
__global__ __launch_bounds__(256) void gemm_scores(const unsigned short* __restrict__ xh,
                                                   const unsigned short* __restrict__ Bht,
                                                   float* __restrict__ S) {
    __shared__ unsigned short ldsA[128 * 128];   // 32 KB
    __shared__ unsigned short ldsB[128 * 128];   // 32 KB
    const int t = threadIdx.x, w = t >> 6, lane = t & 63;
    const int m0 = blockIdx.x * 128;
    const int nsplit = blockIdx.y;               // 16 clusters per split
    const int wm = w & 1, wn = w >> 1;

    // ---- stage A (once) and B tile 0 ----
    {
        const int rl = lane >> 4;                 // row within 4-row group
        const int p  = lane & 15;                 // physical colblock
        #pragma unroll
        for (int q = 0; q < 8; ++q) {
            const int row = w * 32 + q * 4 + rl;
            const int c = p ^ (row & 15);         // source colblock
            gl_lds16(xh + (size_t)(m0 + row) * 128 + c * 8,
                     &ldsA[(w * 32 + q * 4) * 128]);
            gl_lds16(Bht + (size_t)(nsplit * 1024 + row) * 128 + c * 8,
                     &ldsB[(w * 32 + q * 4) * 128]);
        }
    }
    __syncthreads();

    // ---- load all A-fragments into registers (64 VGPRs), resident ----
    s16x8 af[4][4];   // [mt][ks]
    #pragma unroll
    for (int mt = 0; mt < 4; ++mt) {
        const int r = wm * 64 + mt * 16 + (lane & 15);
        #pragma unroll
        for (int ks = 0; ks < 4; ++ks) {
            const int p = (ks * 4 + (lane >> 4)) ^ (lane & 15);
            af[mt][ks] = *(const s16x8*)&ldsA[r * 128 + p * 8];
        }
    }

    #pragma unroll 1
    for (int it = 0; it < 8; ++it) {
        // ---- read this tile's B-fragments ----
        s16x8 bf[4][4];   // [nt][ks]
        #pragma unroll
        for (int nt = 0; nt < 4; ++nt) {
            const int r = wn * 64 + nt * 16 + (lane & 15);
            #pragma unroll
            for (int ks = 0; ks < 4; ++ks) {
                const int p = (ks * 4 + (lane >> 4)) ^ (lane & 15);
                bf[nt][ks] = *(const s16x8*)&ldsB[r * 128 + p * 8];
            }
        }
        __syncthreads();   // all waves done reading ldsB (and ldsA on it=0)

        // ---- kick DMA for next B tile (overlaps the MFMAs below) ----
        if (it < 7) {
            const int rl = lane >> 4, p = lane & 15;
            #pragma unroll
            for (int q = 0; q < 8; ++q) {
                const int row = w * 32 + q * 4 + rl;
                const int c = p ^ (row & 15);
                gl_lds16(Bht + (size_t)(nsplit * 1024 + (it + 1) * 128 + row) * 128 + c * 8,
                         &ldsB[(w * 32 + q * 4) * 128]);
            }
        }

        // ---- MFMAs + interleaved per-mt epilogue ----
        const int nc = nsplit * 16 + it * 2 + wn;
        #pragma unroll
        for (int mt = 0; mt < 4; ++mt) {
            f32x4 acc[4];
            #pragma unroll
            for (int nt = 0; nt < 4; ++nt) acc[nt] = (f32x4){0.f, 0.f, 0.f, 0.f};
            #pragma unroll
            for (int ks = 0; ks < 4; ++ks)
                #pragma unroll
                for (int nt = 0; nt < 4; ++nt)
                    acc[nt] = __builtin_amdgcn_mfma_f32_16x16x32_bf16(
                        af[mt][ks], bf[nt][ks], acc[nt], 0, 0, 0);
            // epilogue for this mt (VALU; overlaps next mt's MFMA pipe)
            #pragma unroll
            for (int rg = 0; rg < 4; ++rg) {
                float p = 0.0f;
                #pragma unroll
                for (int nt = 0; nt < 4; ++nt) {
                    const float v = acc[nt][rg];
                    p += v * v;
                }
                p += __shfl_xor(p, 1, 64);
                p += __shfl_xor(p, 2, 64);
                p += __shfl_xor(p, 4, 64);
                p += __shfl_xor(p, 8, 64);
                if ((lane & 15) == 0) {
                    const int m = wm * 64 + mt * 16 + (lane >> 4) * 4 + rg;
                    S[(size_t)nc * B_N + m0 + m] = p;
                }
            }
        }
        __syncthreads();   // drains this wave's DMA -> ldsB holds tile it+1
    }
}

// ---------------------------------------------------------------------------
// Kernel 3: argmax + loss + exact rescore. Rescore dot rewritten with 4
// independent accumulators + full unroll: 128 independent global loads in
// flight instead of serial 8-load vmcnt batches (the R6-R8 hidden cost).
// ---------------------------------------------------------------------------
__global__ __launch_bounds__(256) void argmax_rescore(const float* __restrict__ Sa,
                                                      const float* __restrict__ nrm,
                                                      const float* __restrict__ x,
                                                      const float* __restrict__ Qg,
                                                      float* __restrict__ out) {
    __shared__ float tile[64 * 65];   // [sample][n], 16640 B
    __shared__ int sflags[64];
    __shared__ int scnt;
    __shared__ float ssum;
    __shared__ float scorr[4];
    const int t = threadIdx.x, w = t >> 6, lane = t & 63;
    const int b0 = blockIdx.x * 64;
    if (t == 0) scnt = 0;

    // coalesced load + transpose: Sa[n][b0 + c] -> tile[c][n]
    for (int idx = t; idx < 1024; idx += 256) {
        const int n = idx >> 4, c4 = idx & 15;
        const f32x4 v = *(const f32x4*)&Sa[(size_t)n * B_N + b0 + c4 * 4];
        tile[(c4 * 4 + 0) * 65 + n] = v.x;
        tile[(c4 * 4 + 1) * 65 + n] = v.y;
        tile[(c4 * 4 + 2) * 65 + n] = v.z;
        tile[(c4 * 4 + 3) * 65 + n] = v.w;
    }
    __syncthreads();

    // per-thread argmax (wave 0), flag near-ties, wave-reduced loss
    if (t < 64) {
        float v1 = -1e30f, v2 = -1e30f;
        int n1 = 0;
        for (int n = 0; n < 64; ++n) {
            const float v = tile[t * 65 + n];
            if (v > v1) { v2 = v1; v1 = v; n1 = n; }
            else v2 = fmaxf(v2, v);
        }
        out[1 + b0 + t] = (float)n1;
        if (v1 - v2 < TAU) { const int i = atomicAdd(&scnt, 1); sflags[i] = t; }
        float err = nrm[b0 + t] - v1;
        for (int off = 32; off; off >>= 1) err += __shfl_xor(err, off, 64);
        if (t == 0) ssum = err;
    }
    if (lane == 0) scorr[w] = 0.0f;
    __syncthreads();

    // cooperative exact rescore of flagged samples (S column from LDS)
    const int nf = scnt;
    float corr = 0.0f;
    for (int f = w; f < nf; f += 4) {
        const int s = sflags[f];
        const int b2 = b0 + s;
        const float v = tile[s * 65 + lane];
        float vm = v;
        for (int off = 32; off; off >>= 1) vm = fmaxf(vm, __shfl_xor(vm, off, 64));
        unsigned long long mask = __ballot((vm - v) < TAU);
        float best = -1e30f;
        int bn = 0;
        while (mask) {
            const int nn = (int)__builtin_ctzll(mask);
            mask &= mask - 1;
            const float* Qn = Qg + (size_t)nn * 8192;
            const float* xb = x + (size_t)b2 * 128;
            float d0 = 0.0f, d1 = 0.0f, d2 = 0.0f, d3 = 0.0f;
            #pragma unroll
            for (int i = 0; i < 128; i += 4) {
                d0 = fmaf(Qn[(i + 0) * 64 + lane], xb[i + 0], d0);
                d1 = fmaf(Qn[(i + 1) * 64 + lane], xb[i + 1], d1);
                d2 = fmaf(Qn[(i + 2) * 64 + lane], xb[i + 2], d2);
                d3 = fmaf(Qn[(i + 3) * 64 + lane], xb[i + 3], d3);
            }
            const float dot = (d0 + d1) + (d2 + d3);
            float sv = dot * dot;
            for (int off = 32; off; off >>= 1) sv += __shfl_xor(sv, off, 64);
            if (sv > best) { best = sv; bn = nn; }
        }
        if (lane == 0) {
            out[1 + b2] = (float)bn;
            corr += vm - best;   // replace approx top score with exact best
        }
    }
    if (lane == 0 && corr != 0.0f) scorr[w] += corr;
    __syncthreads();
    if (t == 0)
        atomicAdd(out, ssum + scorr[0] + scorr[1] + scorr[2] + scorr[3]);
}

// ---------------------------------------------------------------------------
extern "C" void kernel_launch(void* const* d_in, const int* in_sizes, int n_in,
                              void* d_out, int out_size, void* d_ws, size_t ws_size,
                              hipStream_t stream) {
    const float* x = (const float*)d_in[0];   // [16384, 128]
    const float* D = (const float*)d_in[1];   // [64, 128, 64]
    float* out = (float*)d_out;               // [1 + 16384]

    char* ws = (char*)d_ws;
    unsigned short* xh  = (unsigned short*)(ws);                 // 4 MB
    unsigned short* Bht = (unsigned short*)(ws + (4u << 20));    // 1 MB
    float* Qg           = (float*)(ws + (5u << 20));             // 2 MB
    float* Sa           = (float*)(ws + (7u << 20));             // 4 MB
    float* nrm          = (float*)(ws + (11u << 20));            // 64 KB

    prep_convert<<<320, 256, 0, stream>>>(x, D, xh, nrm, Qg, Bht, out);
    gemm_scores<<<dim3(128, 4), 256, 0, stream>>>(xh, Bht, Sa);
    argmax_rescore<<<256, 256, 0, stream>>>(Sa, nrm, x, Qg, out);
}